// Round 4
// baseline (907.351 us; speedup 1.0000x reference)
//
#include <hip/hip_runtime.h>

// Problem constants (match reference setup_inputs)
#define NB 4096   // batch
#define TT 128    // seq len
#define EE 256    // embed dim
#define HH 64     // head dim

typedef __attribute__((ext_vector_type(8))) short bf16x8;
typedef __attribute__((ext_vector_type(4))) float f32x4;
typedef __attribute__((ext_vector_type(2))) unsigned int u32x2;

// LDS strides (in bf16 elements). All multiples of 8 -> 16B-aligned rows,
// and row stride in banks is 32+4 -> +4-bank stagger per row.
#define QK_STRIDE 72    // q,k: [128][72]
#define P_STRIDE  136   // p:   [128][136] (aliases q+k region)
#define VT_STRIDE 136   // vT:  [64][136]

__device__ __forceinline__ unsigned short f2bf(float f) {
  union { float f; unsigned u; } c; c.f = f;
  // round-to-nearest-even bf16
  return (unsigned short)((c.u + 0x7fffu + ((c.u >> 16) & 1u)) >> 16);
}

// Packed f32x2 -> bf16x2 (single VALU inst; no builtin on gfx950, see T12/m240)
__device__ __forceinline__ unsigned cvt_pk(float lo, float hi) {
  unsigned r;
  asm("v_cvt_pk_bf16_f32 %0, %1, %2" : "=v"(r) : "v"(lo), "v"(hi));
  return r;
}

__device__ __forceinline__ bf16x8 cvt8(f32x4 a, f32x4 b) {
  union { unsigned u[4]; bf16x8 v; } r;
  r.u[0] = cvt_pk(a[0], a[1]);
  r.u[1] = cvt_pk(a[2], a[3]);
  r.u[2] = cvt_pk(b[0], b[1]);
  r.u[3] = cvt_pk(b[2], b[3]);
  return r.v;
}

// Convert Wq|Wk|Wv (each [E][H] fp32) into wt[192][256] bf16, transposed so
// that wt[n][e] = W_{n/64}[e][n%64]. LDS-tiled transpose: coalesced 256B reads
// (lane strides along h) and coalesced 128B bf16 writes (lane strides along e).
__global__ void prep_w(const float* __restrict__ wq, const float* __restrict__ wk,
                       const float* __restrict__ wv, unsigned short* __restrict__ wt) {
  __shared__ float tile[64][65];   // +1 pad: conflict-free transposed read
  const int wi = blockIdx.x >> 2;        // which W (0=q,1=k,2=v)
  const int et = blockIdx.x & 3;         // e-tile 0..3 (64 e's each)
  const float* __restrict__ w = (wi == 0) ? wq : (wi == 1) ? wk : wv;
  const int tx = threadIdx.x & 63;
  const int ty = threadIdx.x >> 6;       // 0..3
#pragma unroll
  for (int it = 0; it < 16; ++it) {
    int el = ty + 4 * it;                // e_local 0..63
    tile[el][tx] = w[(et * 64 + el) * HH + tx];   // coalesced: 64 consecutive h
  }
  __syncthreads();
#pragma unroll
  for (int it = 0; it < 16; ++it) {
    int nl = ty + 4 * it;                // n_local 0..63
    wt[(wi * 64 + nl) * EE + et * 64 + tx] = f2bf(tile[tx][nl]);
  }
}

// One third of the QKV projection (n-tiles NTB..NTB+3; NTB in {0,4,8} -> the
// pass writes purely Q, purely K, or purely V^T). x comes from registers (xr),
// loaded ONCE per block -- no global traffic inside the pass. acc is 32 VGPRs
// so phase-1 peak (xr 64 + acc 32 + b 32 + misc) stays <=168 -> 3 waves/SIMD.
template <int NTB>
__device__ __forceinline__ void qkv_pass4(const bf16x8 xr[2][8],
                                          const unsigned short* __restrict__ wt,
                                          unsigned short* qbuf, unsigned short* kbuf,
                                          unsigned short* sVT,
                                          int r0, int r1, int l16, int quad) {
  const int rb[2] = {r0, r1};
  f32x4 acc[4][2];
#pragma unroll
  for (int j = 0; j < 4; ++j)
#pragma unroll
    for (int mt = 0; mt < 2; ++mt)
      acc[j][mt] = (f32x4){0.f, 0.f, 0.f, 0.f};

  // 1-deep rotating wt B-fragment prefetch (L2-resident, ~200cy; partial
  // in-wave cover, rest hidden by co-resident waves).
  bf16x8 bcur[4];
#pragma unroll
  for (int j = 0; j < 4; ++j)
    bcur[j] = *(const bf16x8*)(wt + ((NTB + j) * 16 + l16) * EE + quad * 8);

#pragma unroll
  for (int kc = 0; kc < 8; ++kc) {   // K chunks of 32
    bf16x8 bnext[4];
    if (kc < 7) {
#pragma unroll
      for (int j = 0; j < 4; ++j)
        bnext[j] = *(const bf16x8*)(wt + ((NTB + j) * 16 + l16) * EE + (kc + 1) * 32 + quad * 8);
    }
    __builtin_amdgcn_s_setprio(1);
#pragma unroll
    for (int j = 0; j < 4; ++j) {
      acc[j][0] = __builtin_amdgcn_mfma_f32_16x16x32_bf16(xr[0][kc], bcur[j], acc[j][0], 0, 0, 0);
      acc[j][1] = __builtin_amdgcn_mfma_f32_16x16x32_bf16(xr[1][kc], bcur[j], acc[j][1], 0, 0, 0);
    }
    __builtin_amdgcn_s_setprio(0);
#pragma unroll
    for (int j = 0; j < 4; ++j) bcur[j] = bnext[j];  // rotate (renamed, no copies)
  }

  // Scatter to LDS as bf16. C-layout: row = 4*quad + reg, col = l16 per tile.
  // NTB selects the destination at compile time (0->Q, 4->K, 8->V^T).
#pragma unroll
  for (int j = 0; j < 4; ++j) {
#pragma unroll
    for (int mt = 0; mt < 2; ++mt) {
      const int rbase = rb[mt] + 4 * quad;
      unsigned p01 = cvt_pk(acc[j][mt][0], acc[j][mt][1]);
      unsigned p23 = cvt_pk(acc[j][mt][2], acc[j][mt][3]);
      if (NTB == 0) {
        unsigned short* dst = qbuf + rbase * QK_STRIDE + j * 16 + l16;
        dst[0]             = (unsigned short)p01;
        dst[QK_STRIDE]     = (unsigned short)(p01 >> 16);
        dst[2 * QK_STRIDE] = (unsigned short)p23;
        dst[3 * QK_STRIDE] = (unsigned short)(p23 >> 16);
      } else if (NTB == 4) {
        unsigned short* dst = kbuf + rbase * QK_STRIDE + j * 16 + l16;
        dst[0]             = (unsigned short)p01;
        dst[QK_STRIDE]     = (unsigned short)(p01 >> 16);
        dst[2 * QK_STRIDE] = (unsigned short)p23;
        dst[3 * QK_STRIDE] = (unsigned short)(p23 >> 16);
      } else {
        // V^T rows contiguous along t -> one 8B packed store (rbase%4==0).
        u32x2 pv = {p01, p23};
        *(u32x2*)(sVT + (j * 16 + l16) * VT_STRIDE + rbase) = pv;
      }
    }
  }
}

__global__ __launch_bounds__(256, 3)
void attn_fused(const float* __restrict__ x, const unsigned short* __restrict__ wt,
                float* __restrict__ out) {
  // Region A: Q[128][72] + K[128][72] bf16 = 36864 B; later reused for P[128][136] (34816 B)
  __shared__ __align__(16) unsigned short sQK[2 * TT * QK_STRIDE];
  // Region B: V^T[64][136] bf16 = 17408 B
  __shared__ __align__(16) unsigned short sVT[HH * VT_STRIDE];
  unsigned short* qbuf = sQK;
  unsigned short* kbuf = sQK + TT * QK_STRIDE;
  unsigned short* pbuf = sQK;  // alias, valid after the post-S barrier

  const int b    = blockIdx.x;
  const int tid  = threadIdx.x;
  const int w    = tid >> 6;    // wave 0..3
  const int lane = tid & 63;
  const int quad = lane >> 4;   // 0..3
  const int l16  = lane & 15;

  // Balanced causal decomposition: 8 m-tiles of 16 rows; wave w owns tiles
  // {w, 7-w} -> every wave does 9 units of QK^T/softmax and 5 PV k-steps.
  const int t0 = w, t1 = 7 - w;
  const int rb[2]  = {16 * t0, 16 * t1};    // tile row bases
  const int ntn[2] = {t0 + 1, t1 + 1};      // valid 16-col n-tiles (causal)

  const float* __restrict__ xb = x + (size_t)b * TT * EE;

  // ---------------- Phase 0: stream this wave's x tile (32 rows x 256 cols)
  // into bf16 registers ONCE. 4-chunk fp32 landing pipeline: ~128 B/lane in
  // flight -> 8 KB/wave outstanding -> HBM-saturating at >=8 waves/CU.
  // R3 counters: 2-deep per-pass prefetch left ~600cy exposed per kc-step and
  // the x tile was re-loaded per pass (L2 hid the bytes, not the latency).
  bf16x8 xr[2][8];   // [mt][kc], 64 VGPRs, live through all 3 passes
  {
    f32x4 land[4][2];  // rotating landing slots (32 VGPRs)
#pragma unroll
    for (int c = 0; c < 4; ++c) {     // issue chunks 0..3
      const int kc = c >> 1, mt = c & 1;
      const float* s = xb + (rb[mt] + l16) * EE + kc * 32 + quad * 8;
      land[c][0] = *(const f32x4*)s;
      land[c][1] = *(const f32x4*)(s + 4);
    }
#pragma unroll
    for (int c = 0; c < 16; ++c) {    // drain c, refill c+4
      const int kc = c >> 1, mt = c & 1;
      xr[mt][kc] = cvt8(land[c & 3][0], land[c & 3][1]);
      if (c + 4 < 16) {
        const int cn = c + 4, kcn = cn >> 1, mtn = cn & 1;
        const float* s = xb + (rb[mtn] + l16) * EE + kcn * 32 + quad * 8;
        land[c & 3][0] = *(const f32x4*)s;
        land[c & 3][1] = *(const f32x4*)(s + 4);
      }
    }
  }

  // ---------------- Phase 1: [Q|K|V] = x @ [Wq|Wk|Wv]  (M=128, N=192, K=256)
  // Three register-lean passes (4 n-tiles each), x entirely from registers.
  qkv_pass4<0>(xr, wt, qbuf, kbuf, sVT, rb[0], rb[1], l16, quad);
  qkv_pass4<4>(xr, wt, qbuf, kbuf, sVT, rb[0], rb[1], l16, quad);
  qkv_pass4<8>(xr, wt, qbuf, kbuf, sVT, rb[0], rb[1], l16, quad);
  __syncthreads();

  // ---------------- Phase 2: S = Q K^T / 8, causal, softmax -> P (bf16, LDS)
  f32x4 sacc[2][8];
#pragma unroll
  for (int i = 0; i < 2; ++i)
#pragma unroll
    for (int nt = 0; nt < 8; ++nt)
      sacc[i][nt] = (f32x4){0.f, 0.f, 0.f, 0.f};

#pragma unroll
  for (int kk = 0; kk < 2; ++kk) {   // head dim 64 -> 2 K-steps
#pragma unroll
    for (int i = 0; i < 2; ++i) {
      bf16x8 aq = *(const bf16x8*)(qbuf + (rb[i] + l16) * QK_STRIDE + kk * 32 + quad * 8);
      __builtin_amdgcn_s_setprio(1);
#pragma unroll
      for (int nt = 0; nt < 8; ++nt) {
        if (nt < ntn[i]) {   // wave-uniform predicate
          bf16x8 bk = *(const bf16x8*)(kbuf + (nt * 16 + l16) * QK_STRIDE + kk * 32 + quad * 8);
          sacc[i][nt] = __builtin_amdgcn_mfma_f32_16x16x32_bf16(aq, bk, sacc[i][nt], 0, 0, 0);
        }
      }
      __builtin_amdgcn_s_setprio(0);
    }
  }
  __syncthreads();  // all waves done reading q/k -> region reusable as P

  // Softmax in registers; each (i,reg) pair is one full row spread across the
  // 16 lanes of this quad (cols l16 + 16*nt).
  const float scale = 0.125f;  // 1/sqrt(64)
#pragma unroll
  for (int i = 0; i < 2; ++i) {
    const int ntnW = ntn[i];                 // wave-uniform
    const int ntnPad = (ntnW + 1) & ~1;      // round up to even (PV reads 32-wide)
#pragma unroll
    for (int r = 0; r < 4; ++r) {
      int row = rb[i] + 4 * quad + r;
      float mx = -3.0e38f;
#pragma unroll
      for (int nt = 0; nt < 8; ++nt) {
        if (nt < ntnW) {
          int c = nt * 16 + l16;
          float s = (c <= row) ? sacc[i][nt][r] * scale : -3.0e38f;
          sacc[i][nt][r] = s;
          mx = fmaxf(mx, s);
        }
      }
#pragma unroll
      for (int off = 1; off < 16; off <<= 1) mx = fmaxf(mx, __shfl_xor(mx, off, 64));
      float sum = 0.f;
#pragma unroll
      for (int nt = 0; nt < 8; ++nt) {
        if (nt < ntnW) {
          float e = __expf(sacc[i][nt][r] - mx);
          sacc[i][nt][r] = e;
          sum += e;
        }
      }
#pragma unroll
      for (int off = 1; off < 16; off <<= 1) sum += __shfl_xor(sum, off, 64);
      float inv = 1.0f / sum;
      // Packed P writes, zero-padded to an even n-tile count so the 32-wide
      // PV k-steps never read stale LDS (even t -> odd ntnW -> one zero tile).
#pragma unroll
      for (int np = 0; np < 4; ++np) {
        if (2 * np < ntnPad) {
          float v0 = (2 * np     < ntnW) ? sacc[i][2 * np][r] * inv     : 0.f;
          float v1 = (2 * np + 1 < ntnW) ? sacc[i][2 * np + 1][r] * inv : 0.f;
          unsigned p = cvt_pk(v0, v1);
          pbuf[row * P_STRIDE + (2 * np) * 16 + l16]     = (unsigned short)p;
          pbuf[row * P_STRIDE + (2 * np + 1) * 16 + l16] = (unsigned short)(p >> 16);
        }
      }
    }
  }
  // No barrier needed: wave w only reads its own P rows below, and V^T was
  // synced after phase 1.

  // ---------------- Phase 3: out = P @ V   (per tile: M=16, N=64, K=32*(t/2+1))
  f32x4 oacc[2][4];
#pragma unroll
  for (int i = 0; i < 2; ++i)
#pragma unroll
    for (int nt = 0; nt < 4; ++nt)
      oacc[i][nt] = (f32x4){0.f, 0.f, 0.f, 0.f};

  const int ksn[2] = {t0 / 2 + 1, t1 / 2 + 1};   // 32-wide k-steps (causal-clipped)
#pragma unroll
  for (int i = 0; i < 2; ++i) {
#pragma unroll
    for (int ks = 0; ks < 4; ++ks) {
      if (ks < ksn[i]) {   // wave-uniform
        bf16x8 ap = *(const bf16x8*)(pbuf + (rb[i] + l16) * P_STRIDE + ks * 32 + quad * 8);
        __builtin_amdgcn_s_setprio(1);
#pragma unroll
        for (int nt = 0; nt < 4; ++nt) {
          bf16x8 bv = *(const bf16x8*)(sVT + (nt * 16 + l16) * VT_STRIDE + ks * 32 + quad * 8);
          oacc[i][nt] = __builtin_amdgcn_mfma_f32_16x16x32_bf16(ap, bv, oacc[i][nt], 0, 0, 0);
        }
        __builtin_amdgcn_s_setprio(0);
      }
    }
  }

  float* __restrict__ ob = out + (size_t)b * TT * HH;
#pragma unroll
  for (int i = 0; i < 2; ++i) {
#pragma unroll
    for (int r = 0; r < 4; ++r) {
      int row = rb[i] + 4 * quad + r;
#pragma unroll
      for (int nt = 0; nt < 4; ++nt)
        ob[row * HH + nt * 16 + l16] = oacc[i][nt][r];
    }
  }
}

extern "C" void kernel_launch(void* const* d_in, const int* in_sizes, int n_in,
                              void* d_out, int out_size, void* d_ws, size_t ws_size,
                              hipStream_t stream) {
  const float* x  = (const float*)d_in[0];
  const float* wq = (const float*)d_in[1];
  const float* wk = (const float*)d_in[2];
  const float* wv = (const float*)d_in[3];
  unsigned short* wt = (unsigned short*)d_ws;  // 192*256*2 = 98304 B
  float* outp = (float*)d_out;

  prep_w<<<dim3(12), dim3(256), 0, stream>>>(wq, wk, wv, wt);
  attn_fused<<<dim3(NB), dim3(256), 0, stream>>>(x, wt, outp);
}

// Round 6
// 885.795 us; speedup vs baseline: 1.0243x; 1.0243x over previous
//
#include <hip/hip_runtime.h>

// Problem constants (match reference setup_inputs)
#define NB 4096   // batch
#define TT 128    // seq len
#define EE 256    // embed dim
#define HH 64     // head dim

typedef __attribute__((ext_vector_type(8))) short bf16x8;
typedef __attribute__((ext_vector_type(4))) float f32x4;
typedef __attribute__((ext_vector_type(2))) unsigned int u32x2;

// LDS strides (in bf16 elements).
// QK_STRIDE 68: rows are 136 B apart (8B-aligned only) -> phase-2 fragment
// loads use paired 8B reads. This shrinks Q+K to 34816 B so total LDS is
// 52224 B -> 3 blocks/CU (156672 <= 163840 with 7 KiB margin). R3/R4 counters
// showed only ~1.85 blocks resident at 54272 B (1 KiB margin was not enough).
#define QK_STRIDE 68    // q,k: [128][68]
#define P_STRIDE  136   // p:   [128][136] (aliases q+k region: 17408 elem exact)
#define VT_STRIDE 136   // vT:  [64][136]

__device__ __forceinline__ unsigned short f2bf(float f) {
  union { float f; unsigned u; } c; c.f = f;
  // round-to-nearest-even bf16
  return (unsigned short)((c.u + 0x7fffu + ((c.u >> 16) & 1u)) >> 16);
}

// Packed f32x2 -> bf16x2 (single VALU inst; no builtin on gfx950, see T12/m240)
__device__ __forceinline__ unsigned cvt_pk(float lo, float hi) {
  unsigned r;
  asm("v_cvt_pk_bf16_f32 %0, %1, %2" : "=v"(r) : "v"(lo), "v"(hi));
  return r;
}

__device__ __forceinline__ bf16x8 cvt8(f32x4 a, f32x4 b) {
  union { unsigned u[4]; bf16x8 v; } r;
  r.u[0] = cvt_pk(a[0], a[1]);
  r.u[1] = cvt_pk(a[2], a[3]);
  r.u[2] = cvt_pk(b[0], b[1]);
  r.u[3] = cvt_pk(b[2], b[3]);
  return r.v;
}

// 16-byte LDS fragment load from an 8B-aligned address (two b64 reads).
__device__ __forceinline__ bf16x8 lds_ld8(const unsigned short* p) {
  union { u32x2 d[2]; bf16x8 v; } r;
  r.d[0] = *(const u32x2*)p;
  r.d[1] = *(const u32x2*)(p + 4);
  return r.v;
}

// Convert Wq|Wk|Wv (each [E][H] fp32) into wt[192][256] bf16, transposed so
// that wt[n][e] = W_{n/64}[e][n%64]. LDS-tiled transpose: coalesced 256B reads
// (lane strides along h) and coalesced 128B bf16 writes (lane strides along e).
__global__ void prep_w(const float* __restrict__ wq, const float* __restrict__ wk,
                       const float* __restrict__ wv, unsigned short* __restrict__ wt) {
  __shared__ float tile[64][65];   // +1 pad: conflict-free transposed read
  const int wi = blockIdx.x >> 2;        // which W (0=q,1=k,2=v)
  const int et = blockIdx.x & 3;         // e-tile 0..3 (64 e's each)
  const float* __restrict__ w = (wi == 0) ? wq : (wi == 1) ? wk : wv;
  const int tx = threadIdx.x & 63;
  const int ty = threadIdx.x >> 6;       // 0..3
#pragma unroll
  for (int it = 0; it < 16; ++it) {
    int el = ty + 4 * it;                // e_local 0..63
    tile[el][tx] = w[(et * 64 + el) * HH + tx];   // coalesced: 64 consecutive h
  }
  __syncthreads();
#pragma unroll
  for (int it = 0; it < 16; ++it) {
    int nl = ty + 4 * it;                // n_local 0..63
    wt[(wi * 64 + nl) * EE + et * 64 + tx] = f2bf(tile[tx][nl]);
  }
}

// One half of the QKV projection (n-tiles NTB..NTB+5). Two register-lean
// passes keep the live accumulator set at 48 VGPRs -> no spills (R4 lesson:
// a 64-VGPR x-resident file gets spilled to scratch, costing +118 MB writes).
// x is re-read by the second pass; L2/L3 absorb the bytes (R3: FETCH ~= x once).
template <int NTB>
__device__ __forceinline__ void qkv_pass(const float* __restrict__ xb,
                                         const unsigned short* __restrict__ wt,
                                         unsigned short* qbuf, unsigned short* kbuf,
                                         unsigned short* sVT,
                                         int r0, int r1, int l16, int quad) {
  const int rb[2] = {r0, r1};
  f32x4 acc[6][2];
#pragma unroll
  for (int j = 0; j < 6; ++j)
#pragma unroll
    for (int mt = 0; mt < 2; ++mt)
      acc[j][mt] = (f32x4){0.f, 0.f, 0.f, 0.f};

  // 2-deep rotating x prefetch: HBM latency spans two K-steps of MFMA + wt loads.
  f32x4 xf[2][2][2];  // [buf][mt][half]
#pragma unroll
  for (int p = 0; p < 2; ++p)
#pragma unroll
    for (int mt = 0; mt < 2; ++mt) {
      const float* s = xb + (rb[mt] + l16) * EE + p * 32 + quad * 8;
      xf[p][mt][0] = *(const f32x4*)s;
      xf[p][mt][1] = *(const f32x4*)(s + 4);
    }

  // 1-deep rotating wt B-fragment prefetch: each ~200cy L2 load spans a full
  // 12-MFMA cluster instead of being issued in its consuming step.
  bf16x8 bcur[6];
#pragma unroll
  for (int j = 0; j < 6; ++j)
    bcur[j] = *(const bf16x8*)(wt + ((NTB + j) * 16 + l16) * EE + quad * 8);

#pragma unroll
  for (int kc = 0; kc < 8; ++kc) {   // K chunks of 32
    const int pb = kc & 1;
    bf16x8 afr[2];
    afr[0] = cvt8(xf[pb][0][0], xf[pb][0][1]);
    afr[1] = cvt8(xf[pb][1][0], xf[pb][1][1]);
    if (kc < 6) {  // issue x loads for kc+2 into the buffer just consumed
#pragma unroll
      for (int mt = 0; mt < 2; ++mt) {
        const float* s = xb + (rb[mt] + l16) * EE + (kc + 2) * 32 + quad * 8;
        xf[pb][mt][0] = *(const f32x4*)s;
        xf[pb][mt][1] = *(const f32x4*)(s + 4);
      }
    }
    bf16x8 bnext[6];
    if (kc < 7) {
#pragma unroll
      for (int j = 0; j < 6; ++j)
        bnext[j] = *(const bf16x8*)(wt + ((NTB + j) * 16 + l16) * EE + (kc + 1) * 32 + quad * 8);
    }
    __builtin_amdgcn_s_setprio(1);
#pragma unroll
    for (int j = 0; j < 6; ++j) {
      acc[j][0] = __builtin_amdgcn_mfma_f32_16x16x32_bf16(afr[0], bcur[j], acc[j][0], 0, 0, 0);
      acc[j][1] = __builtin_amdgcn_mfma_f32_16x16x32_bf16(afr[1], bcur[j], acc[j][1], 0, 0, 0);
    }
    __builtin_amdgcn_s_setprio(0);
#pragma unroll
    for (int j = 0; j < 6; ++j) bcur[j] = bnext[j];  // rotate (renamed, no copies)
  }

  // Scatter Q,K ([t][h] row-major) and V^T ([h][t]) to LDS as bf16.
  // C-layout: row = 4*quad + reg, col = l16 within each 16x16 tile.
#pragma unroll
  for (int j = 0; j < 6; ++j) {
    const int nt = NTB + j;           // compile-time
    const int cg = nt * 16 + l16;     // combined col 0..191
#pragma unroll
    for (int mt = 0; mt < 2; ++mt) {
      const int rbase = rb[mt] + 4 * quad;
      unsigned p01 = cvt_pk(acc[j][mt][0], acc[j][mt][1]);
      unsigned p23 = cvt_pk(acc[j][mt][2], acc[j][mt][3]);
      if (nt < 8) {
        unsigned short* dst = (nt < 4) ? (qbuf + rbase * QK_STRIDE + cg)
                                       : (kbuf + rbase * QK_STRIDE + (cg - 64));
        dst[0]             = (unsigned short)p01;
        dst[QK_STRIDE]     = (unsigned short)(p01 >> 16);
        dst[2 * QK_STRIDE] = (unsigned short)p23;
        dst[3 * QK_STRIDE] = (unsigned short)(p23 >> 16);
      } else {
        // V^T rows contiguous along t -> one 8B packed store (rbase%4==0).
        u32x2 pv = {p01, p23};
        *(u32x2*)(sVT + (cg - 128) * VT_STRIDE + rbase) = pv;
      }
    }
  }
}

__global__ __launch_bounds__(256, 3)
void attn_fused(const float* __restrict__ x, const unsigned short* __restrict__ wt,
                float* __restrict__ out) {
  // Region A: Q[128][68] + K[128][68] bf16 = 34816 B; reused for P[128][136]
  // (exactly 17408 elem). Region B: V^T[64][136] = 17408 B. Total 52224 B.
  __shared__ __align__(16) unsigned short sQK[2 * TT * QK_STRIDE];
  __shared__ __align__(16) unsigned short sVT[HH * VT_STRIDE];
  unsigned short* qbuf = sQK;
  unsigned short* kbuf = sQK + TT * QK_STRIDE;
  unsigned short* pbuf = sQK;  // alias, valid after the post-S barrier

  const int b    = blockIdx.x;
  const int tid  = threadIdx.x;
  const int w    = tid >> 6;    // wave 0..3
  const int lane = tid & 63;
  const int quad = lane >> 4;   // 0..3
  const int l16  = lane & 15;

  // Balanced causal decomposition: 8 m-tiles of 16 rows; wave w owns tiles
  // {w, 7-w} -> every wave does 9 units of QK^T/softmax and 5 PV k-steps.
  const int t0 = w, t1 = 7 - w;
  const int rb[2]  = {16 * t0, 16 * t1};    // tile row bases
  const int ntn[2] = {t0 + 1, t1 + 1};      // valid 16-col n-tiles (causal)

  const float* __restrict__ xb = x + (size_t)b * TT * EE;

  // ---------------- Phase 1: [Q|K|V] = x @ [Wq|Wk|Wv]  (M=128, N=192, K=256)
  qkv_pass<0>(xb, wt, qbuf, kbuf, sVT, rb[0], rb[1], l16, quad);
  qkv_pass<6>(xb, wt, qbuf, kbuf, sVT, rb[0], rb[1], l16, quad);
  __syncthreads();

  // ---------------- Phase 2: S = Q K^T / 8, causal, softmax -> P (bf16, LDS)
  f32x4 sacc[2][8];
#pragma unroll
  for (int i = 0; i < 2; ++i)
#pragma unroll
    for (int nt = 0; nt < 8; ++nt)
      sacc[i][nt] = (f32x4){0.f, 0.f, 0.f, 0.f};

#pragma unroll
  for (int kk = 0; kk < 2; ++kk) {   // head dim 64 -> 2 K-steps
#pragma unroll
    for (int i = 0; i < 2; ++i) {
      bf16x8 aq = lds_ld8(qbuf + (rb[i] + l16) * QK_STRIDE + kk * 32 + quad * 8);
      __builtin_amdgcn_s_setprio(1);
#pragma unroll
      for (int nt = 0; nt < 8; ++nt) {
        if (nt < ntn[i]) {   // wave-uniform predicate
          bf16x8 bk = lds_ld8(kbuf + (nt * 16 + l16) * QK_STRIDE + kk * 32 + quad * 8);
          sacc[i][nt] = __builtin_amdgcn_mfma_f32_16x16x32_bf16(aq, bk, sacc[i][nt], 0, 0, 0);
        }
      }
      __builtin_amdgcn_s_setprio(0);
    }
  }
  __syncthreads();  // all waves done reading q/k -> region reusable as P

  // Softmax in registers; each (i,reg) pair is one full row spread across the
  // 16 lanes of this quad (cols l16 + 16*nt). P is stored UNNORMALIZED
  // (e^(s-mx) <= 1, bf16-safe); 1/sum is deferred to the fp32 output write,
  // shortening the softmax -> P-write -> PV critical path.
  const float scale = 0.125f;  // 1/sqrt(64)
  float invr[2][4];
#pragma unroll
  for (int i = 0; i < 2; ++i) {
    const int ntnW = ntn[i];                 // wave-uniform
    const int ntnPad = (ntnW + 1) & ~1;      // round up to even (PV reads 32-wide)
#pragma unroll
    for (int r = 0; r < 4; ++r) {
      int row = rb[i] + 4 * quad + r;
      float mx = -3.0e38f;
#pragma unroll
      for (int nt = 0; nt < 8; ++nt) {
        if (nt < ntnW) {
          int c = nt * 16 + l16;
          float s = (c <= row) ? sacc[i][nt][r] * scale : -3.0e38f;
          sacc[i][nt][r] = s;
          mx = fmaxf(mx, s);
        }
      }
#pragma unroll
      for (int off = 1; off < 16; off <<= 1) mx = fmaxf(mx, __shfl_xor(mx, off, 64));
      float sum = 0.f;
#pragma unroll
      for (int nt = 0; nt < 8; ++nt) {
        if (nt < ntnW) {
          float e = __expf(sacc[i][nt][r] - mx);
          sacc[i][nt][r] = e;
          sum += e;
        }
      }
      // Packed unnormalized P writes (zero-padded to an even n-tile count so
      // the 32-wide PV k-steps never read stale LDS). These overlap the sum
      // shuffle-reduce below in the scheduler.
#pragma unroll
      for (int np = 0; np < 4; ++np) {
        if (2 * np < ntnPad) {
          float v0 = (2 * np     < ntnW) ? sacc[i][2 * np][r]     : 0.f;
          float v1 = (2 * np + 1 < ntnW) ? sacc[i][2 * np + 1][r] : 0.f;
          unsigned p = cvt_pk(v0, v1);
          pbuf[row * P_STRIDE + (2 * np) * 16 + l16]     = (unsigned short)p;
          pbuf[row * P_STRIDE + (2 * np + 1) * 16 + l16] = (unsigned short)(p >> 16);
        }
      }
#pragma unroll
      for (int off = 1; off < 16; off <<= 1) sum += __shfl_xor(sum, off, 64);
      invr[i][r] = 1.0f / sum;
    }
  }
  // No barrier needed: wave w only reads its own P rows below, and V^T was
  // synced after phase 1.

  // ---------------- Phase 3: out = P @ V   (per tile: M=16, N=64, K=32*(t/2+1))
  f32x4 oacc[2][4];
#pragma unroll
  for (int i = 0; i < 2; ++i)
#pragma unroll
    for (int nt = 0; nt < 4; ++nt)
      oacc[i][nt] = (f32x4){0.f, 0.f, 0.f, 0.f};

  const int ksn[2] = {t0 / 2 + 1, t1 / 2 + 1};   // 32-wide k-steps (causal-clipped)
#pragma unroll
  for (int i = 0; i < 2; ++i) {
#pragma unroll
    for (int ks = 0; ks < 4; ++ks) {
      if (ks < ksn[i]) {   // wave-uniform
        // P rows are 272 B apart -> 16B aligned, b128 OK.
        bf16x8 ap = *(const bf16x8*)(pbuf + (rb[i] + l16) * P_STRIDE + ks * 32 + quad * 8);
        __builtin_amdgcn_s_setprio(1);
#pragma unroll
        for (int nt = 0; nt < 4; ++nt) {
          bf16x8 bv = *(const bf16x8*)(sVT + (nt * 16 + l16) * VT_STRIDE + ks * 32 + quad * 8);
          oacc[i][nt] = __builtin_amdgcn_mfma_f32_16x16x32_bf16(ap, bv, oacc[i][nt], 0, 0, 0);
        }
        __builtin_amdgcn_s_setprio(0);
      }
    }
  }

  float* __restrict__ ob = out + (size_t)b * TT * HH;
#pragma unroll
  for (int i = 0; i < 2; ++i) {
#pragma unroll
    for (int r = 0; r < 4; ++r) {
      int row = rb[i] + 4 * quad + r;
      float inv = invr[i][r];
#pragma unroll
      for (int nt = 0; nt < 4; ++nt)
        ob[row * HH + nt * 16 + l16] = oacc[i][nt][r] * inv;
    }
  }
}

extern "C" void kernel_launch(void* const* d_in, const int* in_sizes, int n_in,
                              void* d_out, int out_size, void* d_ws, size_t ws_size,
                              hipStream_t stream) {
  const float* x  = (const float*)d_in[0];
  const float* wq = (const float*)d_in[1];
  const float* wk = (const float*)d_in[2];
  const float* wv = (const float*)d_in[3];
  unsigned short* wt = (unsigned short*)d_ws;  // 192*256*2 = 98304 B
  float* outp = (float*)d_out;

  prep_w<<<dim3(12), dim3(256), 0, stream>>>(wq, wk, wv, wt);
  attn_fused<<<dim3(NB), dim3(256), 0, stream>>>(x, wt, outp);
}